// Round 14
// baseline (403.185 us; speedup 1.0000x reference)
//
#include <hip/hip_runtime.h>
#include <hip/hip_bf16.h>
#include <math.h>

#define NN 50000
#define NG 128
#define INC 128
#define HIDC 256
#define NCLS 10

#define NBLK 256   // partition chunks
#define BSH 8      // bucket = col >> 8
#define NB 196     // ceil(50000/256) buckets

typedef _Float16 h8_t __attribute__((ext_vector_type(8)));  // 8 fp16 (4 VGPR)
typedef _Float16 h2_t __attribute__((ext_vector_type(2)));  // packed half2
typedef __attribute__((ext_vector_type(4))) float f4_t;     // 4 f32

__device__ inline f4_t mfma16(h8_t a, h8_t b, f4_t c) {
  return __builtin_amdgcn_mfma_f32_16x16x32_f16(a, b, c, 0, 0, 0);
}

__device__ inline ushort f2h(float f) {
  _Float16 h = (_Float16)f; return *(ushort*)&h;
}
__device__ inline float h2f(ushort u) {
  _Float16 h = *(_Float16*)&u; return (float)h;
}

union U2 { uint2 u; struct { h2_t x, y; } h; };
union UW { unsigned u; h2_t h; };

__device__ inline void gload_lds16(const void* g, void* l) {
  __builtin_amdgcn_global_load_lds(
      (const __attribute__((address_space(1))) unsigned int*)g,
      (__attribute__((address_space(3))) unsigned int*)l, 16, 0, 0);
}

__device__ inline int lbound(const int* __restrict__ a, int n, int key) {
  int lo = 0, hi = n;
  while (lo < hi) { int m = (lo + hi) >> 1; if (a[m] < key) lo = m + 1; else hi = m; }
  return lo;
}

// ---------------- bucketed edge partition ----------------
__global__ __launch_bounds__(256) void edge_hist(const int* __restrict__ ecol,
                                                 int* __restrict__ hist, int E, int chunk) {
  __shared__ int h[NB];
  int blk = blockIdx.x;
  for (int i = threadIdx.x; i < NB; i += 256) h[i] = 0;
  __syncthreads();
  int e0 = blk * chunk, e1 = min(e0 + chunk, E);
  for (int e = e0 + threadIdx.x; e < e1; e += 256)
    atomicAdd(&h[ecol[e] >> BSH], 1);
  __syncthreads();
  for (int i = threadIdx.x; i < NB; i += 256) hist[i * NBLK + blk] = h[i];
}

// part entry: (row << 8) | (col & 255)
__global__ __launch_bounds__(256) void edge_partition(const int* __restrict__ erow,
                                                      const int* __restrict__ ecol,
                                                      const int* __restrict__ histBase,
                                                      unsigned* __restrict__ part,
                                                      int E, int chunk) {
  __shared__ int cur[NB];
  int blk = blockIdx.x;
  for (int i = threadIdx.x; i < NB; i += 256) cur[i] = histBase[i * NBLK + blk];
  __syncthreads();
  int e0 = blk * chunk, e1 = min(e0 + chunk, E);
  for (int e = e0 + threadIdx.x; e < e1; e += 256) {
    int c = ecol[e];
    int b = c >> BSH;
    int pos = atomicAdd(&cur[b], 1);
    part[pos] = ((unsigned)erow[e] << 8) | (unsigned)(c & 255);
  }
}

// count node degrees per bucket; write deg, dis, and bucket padded-total
__global__ __launch_bounds__(256) void bucket_cnt(const unsigned* __restrict__ part,
                                                  const int* __restrict__ histBase,
                                                  int* __restrict__ deg,
                                                  float* __restrict__ dis,
                                                  int* __restrict__ padTot, int N) {
  __shared__ int cnt[256];
  __shared__ int sm[256];
  int b = blockIdx.x, t = threadIdx.x;
  cnt[t] = 0;
  __syncthreads();
  int s0 = histBase[b * NBLK];
  int s1 = histBase[(b + 1) * NBLK];
  for (int e = s0 + t; e < s1; e += 256)
    atomicAdd(&cnt[part[e] & 255], 1);
  __syncthreads();
  int v = cnt[t];
  int pc = (v + 7) & ~7;
  sm[t] = pc;
  __syncthreads();
  #pragma unroll
  for (int off = 1; off < 256; off <<= 1) {
    int x = (t >= off) ? sm[t - off] : 0;
    __syncthreads();
    sm[t] += x;
    __syncthreads();
  }
  int node = (b << BSH) + t;
  if (node < N) {
    deg[node] = v;
    dis[node] = rsqrtf((float)v + 1.0f);
  }
  if (t == 255) padTot[b] = sm[255];
}

__global__ void padscan(int* __restrict__ padTot, int* __restrict__ padBase, int nb) {
  if (threadIdx.x == 0 && blockIdx.x == 0) {
    int run = 0;
    for (int i = 0; i < nb; ++i) { padBase[i] = run; run += padTot[i]; }
  }
}

// fused: offsets (8-aligned) + dend + packed ew write
__global__ __launch_bounds__(256) void bucket_ew(const unsigned* __restrict__ part,
                                                 const int* __restrict__ histBase,
                                                 const int* __restrict__ padBase,
                                                 const int* __restrict__ deg,
                                                 const float* __restrict__ dis,
                                                 int* __restrict__ offsets,
                                                 int* __restrict__ dend,
                                                 unsigned* __restrict__ ew, int N) {
  __shared__ int cur[256];
  __shared__ int sm[256];
  __shared__ float sdis[256];
  int b = blockIdx.x, t = threadIdx.x;
  int node = (b << BSH) + t;
  int v = (node < N) ? deg[node] : 0;
  int pc = (v + 7) & ~7;
  sm[t] = pc;
  sdis[t] = (node < N) ? dis[node] : 0.0f;
  __syncthreads();
  #pragma unroll
  for (int off = 1; off < 256; off <<= 1) {
    int x = (t >= off) ? sm[t - off] : 0;
    __syncthreads();
    sm[t] += x;
    __syncthreads();
  }
  int excl = (t == 0) ? 0 : sm[t - 1];
  int obase = padBase[b] + excl;
  cur[t] = obase;
  if (node < N) {
    offsets[node] = obase;
    dend[node] = obase + v;
  }
  __syncthreads();
  int s0 = histBase[b * NBLK];
  int s1 = histBase[(b + 1) * NBLK];
  for (int e = s0 + t; e < s1; e += 256) {
    unsigned pv = part[e];
    int c = pv & 255;
    int r = (int)(pv >> 8);
    int pos = atomicAdd(&cur[c], 1);
    float w = dis[r] * sdis[c];
    ew[pos] = ((unsigned)r << 16) | (unsigned)f2h(w);
  }
}

// ---------------- multi-block exclusive scan (for histBase only) ----------------
#define SCAN_T 256
#define SCAN_V 8
#define SCAN_VPB (SCAN_T * SCAN_V)  // 2048

__global__ __launch_bounds__(SCAN_T) void scanA(const int* __restrict__ deg,
                                                int* __restrict__ offsets,
                                                int* __restrict__ blockTotals, int n) {
  __shared__ int sm[SCAN_T];
  int b = blockIdx.x;
  int t = threadIdx.x;
  int base = b * SCAN_VPB + t * SCAN_V;
  int v[SCAN_V];
  int run = 0;
  #pragma unroll
  for (int j = 0; j < SCAN_V; ++j) {
    int idx = base + j;
    int d = (idx < n) ? deg[idx] : 0;
    run += d;
    v[j] = run;
  }
  sm[t] = run;
  __syncthreads();
  #pragma unroll
  for (int off = 1; off < SCAN_T; off <<= 1) {
    int x = (t >= off) ? sm[t - off] : 0;
    __syncthreads();
    sm[t] += x;
    __syncthreads();
  }
  int excl = (t == 0) ? 0 : sm[t - 1];
  #pragma unroll
  for (int j = 0; j < SCAN_V; ++j) {
    int idx = base + j;
    if (idx < n) offsets[idx + 1] = v[j] + excl;
  }
  if (t == SCAN_T - 1) blockTotals[b] = sm[t];
}

__global__ void scanB(int* __restrict__ blockTotals, int nb) {
  if (threadIdx.x == 0 && blockIdx.x == 0) {
    int run = 0;
    for (int i = 0; i < nb; ++i) {
      int v = blockTotals[i];
      blockTotals[i] = run;
      run += v;
    }
  }
}

__global__ void scanC(int* __restrict__ offsets, const int* __restrict__ blockTotals, int n) {
  int stride = gridDim.x * blockDim.x;
  for (int i = blockIdx.x * blockDim.x + threadIdx.x; i < n; i += stride) {
    offsets[i + 1] += blockTotals[i / SCAN_VPB];
    if (i == 0) offsets[0] = 0;
  }
}

// ---------------- fused casts ----------------
__global__ void cast_all(const float* __restrict__ x, unsigned* __restrict__ xcb,
                         const float* __restrict__ W1, ushort* __restrict__ W1T,
                         const float* __restrict__ W2, ushort* __restrict__ W2T, int N) {
  int idx = blockIdx.x * 256 + threadIdx.x;
  int nx = N * 64;
  if (idx < nx) {
    int n = idx >> 6, pp = idx & 63;
    float v0 = x[(long)n * 128 + 2 * pp];
    float v1 = x[(long)n * 128 + 2 * pp + 1];
    xcb[((long)(pp >> 4) * N + n) * 16 + (pp & 15)] =
        (unsigned)f2h(v0) | ((unsigned)f2h(v1) << 16);
    return;
  }
  int i1 = idx - nx;
  if (i1 < INC * HIDC) {
    int k = i1 / HIDC, n = i1 % HIDC;
    W1T[(long)n * INC + k] = f2h(W1[i1]);
    return;
  }
  int i2 = i1 - INC * HIDC;
  if (i2 < HIDC * HIDC) {
    int k = i2 / HIDC, n = i2 % HIDC;
    W2T[(long)n * HIDC + k] = f2h(W2[i2]);
  }
}

// ---------------- channel-blocked aggregation, XCD-pinned, packed-fp16, uint4 ew --
// MODE 0 (layer 2, 8 slices): slice = blk&7, nodeblk = blk>>3.
// MODE 1 (layer 1, 4 slices): slice = (blk>>1)&3, sub = blk&1.
// Group = 8 lanes owns one node's 32-ch slice (8 x uint2 = 64B of fp16).
// offsets are 8-aligned; ew read 4-at-a-time via uint4.
template <int MODE>
__global__ __launch_bounds__(256) void aggregate_cb(
    const uint2* __restrict__ xcb, const float* __restrict__ dis,
    const int* __restrict__ offsets, const int* __restrict__ dend,
    const unsigned* __restrict__ ew, uint2* __restrict__ outcb, int N) {
  int blk = blockIdx.x;
  int slice, nb;
  if (MODE == 0) { slice = blk & 7; nb = blk >> 3; }
  else           { slice = (blk >> 1) & 3; nb = ((blk >> 3) << 1) | (blk & 1); }
  int node = nb * 32 + (threadIdx.x >> 3);
  if (node >= N) return;
  int cl = threadIdx.x & 7;
  const uint2* xs = xcb + (long)slice * N * 8;
  uint2* os = outcb + (long)slice * N * 8;
  float di = dis[node];
  _Float16 ddh = (_Float16)(di * di);
  h2_t dd2 = {ddh, ddh};
  U2 sv; sv.u = xs[node * 8 + cl];
  h2_t ax = sv.h.x * dd2, ay = sv.h.y * dd2;
  h2_t bx = {0, 0}, by = {0, 0};
  h2_t cx = {0, 0}, cy = {0, 0};
  h2_t dx = {0, 0}, dy = {0, 0};
  int e = offsets[node], eE = dend[node];
  for (; e + 7 < eE; e += 8) {
    uint4 pa = *(const uint4*)(ew + e);
    uint4 pb = *(const uint4*)(ew + e + 4);
    U2 v0, v1, v2, v3, v4, v5, v6, v7;
    v0.u = xs[(pa.x >> 16) * 8 + cl];
    v1.u = xs[(pa.y >> 16) * 8 + cl];
    v2.u = xs[(pa.z >> 16) * 8 + cl];
    v3.u = xs[(pa.w >> 16) * 8 + cl];
    v4.u = xs[(pb.x >> 16) * 8 + cl];
    v5.u = xs[(pb.y >> 16) * 8 + cl];
    v6.u = xs[(pb.z >> 16) * 8 + cl];
    v7.u = xs[(pb.w >> 16) * 8 + cl];
    UW q0, q1, q2, q3, q4, q5, q6, q7;
    q0.u = pa.x; q1.u = pa.y; q2.u = pa.z; q3.u = pa.w;
    q4.u = pb.x; q5.u = pb.y; q6.u = pb.z; q7.u = pb.w;
    h2_t w0 = {q0.h[0], q0.h[0]}, w1 = {q1.h[0], q1.h[0]};
    h2_t w2 = {q2.h[0], q2.h[0]}, w3 = {q3.h[0], q3.h[0]};
    h2_t w4 = {q4.h[0], q4.h[0]}, w5 = {q5.h[0], q5.h[0]};
    h2_t w6 = {q6.h[0], q6.h[0]}, w7 = {q7.h[0], q7.h[0]};
    ax = v0.h.x * w0 + ax; ay = v0.h.y * w0 + ay;
    bx = v1.h.x * w1 + bx; by = v1.h.y * w1 + by;
    cx = v2.h.x * w2 + cx; cy = v2.h.y * w2 + cy;
    dx = v3.h.x * w3 + dx; dy = v3.h.y * w3 + dy;
    ax = v4.h.x * w4 + ax; ay = v4.h.y * w4 + ay;
    bx = v5.h.x * w5 + bx; by = v5.h.y * w5 + by;
    cx = v6.h.x * w6 + cx; cy = v6.h.y * w6 + cy;
    dx = v7.h.x * w7 + dx; dy = v7.h.y * w7 + dy;
  }
  for (; e < eE; ++e) {
    unsigned p0 = ew[e];
    U2 v0; v0.u = xs[(p0 >> 16) * 8 + cl];
    UW q0; q0.u = p0;
    h2_t w0 = {q0.h[0], q0.h[0]};
    ax = v0.h.x * w0 + ax; ay = v0.h.y * w0 + ay;
  }
  ax = ax + bx + cx + dx;
  ay = ay + by + cy + dy;
  U2 o; o.h.x = ax; o.h.y = ay;
  os[node * 8 + cl] = o.u;
}

// ---------------- MFMA GEMM (128x128 tile, grid.y=2), fp16 ----------------
template <int K, bool OUTCB>
__global__ __launch_bounds__(256) void gemm_mfma(
    const ushort* __restrict__ A, const ushort* __restrict__ WT,
    const float* __restrict__ bias, ushort* __restrict__ outb, int M) {
  __shared__ ushort smem[16384];
  const int tid = threadIdx.x;
  const int lane = tid & 63;
  const int wave = tid >> 6;
  const int wm = wave >> 1, wn = wave & 1;
  const int m0 = blockIdx.x * 128;
  const int n0 = blockIdx.y * 128;

  f4_t acc[4][4] = {};

  for (int k0 = 0; k0 < K; k0 += 64) {
    __syncthreads();
    #pragma unroll
    for (int is = 0; is < 4; ++is) {
      int s = is * 256 + tid;
      int row = s >> 3;
      int ch = (s & 7) ^ (row & 7);
      int k = k0 + ch * 8;
      long grow = m0 + row; if (grow > M - 1) grow = M - 1;
      const ushort* g = A + ((long)(k >> 5) * M + grow) * 32 + (k & 31);
      gload_lds16(g, &smem[(is * 256 + wave * 64) * 8]);
    }
    #pragma unroll
    for (int is = 0; is < 4; ++is) {
      int s = is * 256 + tid;
      int row = s >> 3;
      int ch = (s & 7) ^ (row & 7);
      const ushort* g = WT + (long)(n0 + row) * K + k0 + ch * 8;
      gload_lds16(g, &smem[8192 + (is * 256 + wave * 64) * 8]);
    }
    asm volatile("s_waitcnt vmcnt(0)" ::: "memory");
    __syncthreads();
    #pragma unroll
    for (int ks = 0; ks < 2; ++ks) {
      h8_t af[4], bfr[4];
      #pragma unroll
      for (int mi = 0; mi < 4; ++mi) {
        int row = wm * 64 + mi * 16 + (lane & 15);
        int ch = (ks * 4 + (lane >> 4)) ^ (row & 7);
        af[mi] = *(const h8_t*)(&smem[row * 64 + ch * 8]);
      }
      #pragma unroll
      for (int ni = 0; ni < 4; ++ni) {
        int row = wn * 64 + ni * 16 + (lane & 15);
        int ch = (ks * 4 + (lane >> 4)) ^ (row & 7);
        bfr[ni] = *(const h8_t*)(&smem[8192 + row * 64 + ch * 8]);
      }
      #pragma unroll
      for (int mi = 0; mi < 4; ++mi)
        #pragma unroll
        for (int ni = 0; ni < 4; ++ni)
          acc[mi][ni] = mfma16(af[mi], bfr[ni], acc[mi][ni]);
    }
  }
  #pragma unroll
  for (int ni = 0; ni < 4; ++ni) {
    int col = n0 + wn * 64 + ni * 16 + (lane & 15);
    float bb = bias[col];
    #pragma unroll
    for (int mi = 0; mi < 4; ++mi) {
      #pragma unroll
      for (int r = 0; r < 4; ++r) {
        int row = m0 + wm * 64 + mi * 16 + (lane >> 4) * 4 + r;
        if (row < M) {
          float v = fmaxf(acc[mi][ni][r] + bb, 0.0f);
          if (OUTCB)
            outb[((long)(col >> 5) * M + row) * 32 + (col & 31)] = f2h(v);
          else
            outb[(long)row * HIDC + col] = f2h(v);
        }
      }
    }
  }
}

// ---------------- pool: partial sums, no atomics ----------------
#define POOL_SPLIT 8
__global__ __launch_bounds__(HIDC) void pool_partial(const ushort* __restrict__ h,
                                                     const int* __restrict__ batch,
                                                     float* __restrict__ psum, int N) {
  __shared__ int bounds[2];
  int g = blockIdx.x;
  int s = blockIdx.y;
  int c = threadIdx.x;
  if (c == 0) bounds[0] = lbound(batch, N, g);
  if (c == 1) bounds[1] = lbound(batch, N, g + 1);
  __syncthreads();
  int s0 = bounds[0], s1 = bounds[1];
  int len = s1 - s0;
  int chunk = (len + POOL_SPLIT - 1) / POOL_SPLIT;
  int i0 = s0 + s * chunk;
  int i1 = min(i0 + chunk, s1);
  float acc = 0.0f;
  for (int i = i0; i < i1; ++i) acc += h2f(h[(long)i * HIDC + c]);
  psum[((long)g * POOL_SPLIT + s) * HIDC + c] = acc;
}

// ---------------- final MLP + log_softmax (reduces psum) ----------------
__global__ __launch_bounds__(64) void mlp_kernel(
    const float* __restrict__ psum, const int* __restrict__ batch,
    const float* __restrict__ Wl1, const float* __restrict__ bl1,
    const float* __restrict__ Wl2, const float* __restrict__ bl2,
    float* __restrict__ out, int N) {
  __shared__ float g[HIDC];
  __shared__ float hid[64];
  __shared__ float logits[NCLS];
  __shared__ float red[2];
  int i = blockIdx.x;
  int t = threadIdx.x;
  int cnt = lbound(batch, N, i + 1) - lbound(batch, N, i);
  float inv = 1.0f / fmaxf((float)cnt, 1.0f);
  for (int c = t; c < HIDC; c += 64) {
    float s = 0.0f;
    #pragma unroll
    for (int k = 0; k < POOL_SPLIT; ++k)
      s += psum[((long)i * POOL_SPLIT + k) * HIDC + c];
    g[c] = s * inv;
  }
  __syncthreads();
  float acc = bl1[t];
  for (int c = 0; c < HIDC; ++c) acc = fmaf(g[c], Wl1[c * 64 + t], acc);
  hid[t] = fmaxf(acc, 0.0f);
  __syncthreads();
  if (t < NCLS) {
    float l = bl2[t];
    for (int c = 0; c < 64; ++c) l = fmaf(hid[c], Wl2[c * NCLS + t], l);
    logits[t] = l;
  }
  __syncthreads();
  if (t == 0) {
    float m = -1e30f;
    for (int k = 0; k < NCLS; ++k) m = fmaxf(m, logits[k]);
    float s = 0.f;
    for (int k = 0; k < NCLS; ++k) s += expf(logits[k] - m);
    red[0] = m;
    red[1] = logf(s);
  }
  __syncthreads();
  if (t < NCLS) out[i * NCLS + t] = logits[t] - red[0] - red[1];
}

extern "C" void kernel_launch(void* const* d_in, const int* in_sizes, int n_in,
                              void* d_out, int out_size, void* d_ws, size_t ws_size,
                              hipStream_t stream) {
  const float* x = (const float*)d_in[0];
  const int* edge_index = (const int*)d_in[1];
  const int* batch = (const int*)d_in[2];
  const float* W1 = (const float*)d_in[3];
  const float* b1 = (const float*)d_in[4];
  const float* W2 = (const float*)d_in[5];
  const float* b2 = (const float*)d_in[6];
  const float* Wl1 = (const float*)d_in[7];
  const float* bl1 = (const float*)d_in[8];
  const float* Wl2 = (const float*)d_in[9];
  const float* bl2 = (const float*)d_in[10];
  float* out = (float*)d_out;

  const int N = in_sizes[0] / INC;     // 50000
  const int E = in_sizes[1] / 2;       // 1600000
  const int* erow = edge_index;
  const int* ecol = edge_index + E;

  char* p = (char*)d_ws;
  auto alloc = [&](size_t bytes) {
    void* r = (void*)p;
    p += (bytes + 255) & ~(size_t)255;
    return r;
  };
  float* dis = (float*)alloc((size_t)N * 4);
  int* deg = (int*)alloc((size_t)N * 4);
  int* offsets = (int*)alloc((size_t)(N + 1) * 4);
  int* dend = (int*)alloc((size_t)N * 4);
  unsigned* ew = (unsigned*)alloc(((size_t)E + 8 * (size_t)N) * 4);  // padded
  unsigned* part = (unsigned*)alloc((size_t)E * 4);
  int* hist = (int*)alloc((size_t)(NB * NBLK) * 4);
  int* histBase = (int*)alloc((size_t)(NB * NBLK + 1) * 4);
  int* padTot = (int*)alloc((size_t)NB * 4);
  int* padBase = (int*)alloc((size_t)NB * 4);
  float* psum = (float*)alloc((size_t)NG * POOL_SPLIT * HIDC * 4);
  int* blockTotals = (int*)alloc((size_t)256 * 4);
  ushort* W1T = (ushort*)alloc((size_t)INC * HIDC * 2);
  ushort* W2T = (ushort*)alloc((size_t)HIDC * HIDC * 2);
  unsigned* x_cb = (unsigned*)alloc((size_t)N * INC * 2);      // [4][N][16u]
  unsigned* agg1_cb = (unsigned*)alloc((size_t)N * INC * 2);   // [4][N][16u]
  unsigned* h1_cb = (unsigned*)alloc((size_t)N * HIDC * 2);    // [8][N][16u]
  unsigned* agg2_cb = (unsigned*)alloc((size_t)N * HIDC * 2);  // [8][N][16u]
  ushort* h2 = (ushort*)x_cb;  // reuse (x_cb+agg1_cb dead after GEMM1)

  // bucketed CSR build (padded, 8-aligned per-node runs)
  const int chunk = (E + NBLK - 1) / NBLK;
  edge_hist<<<NBLK, 256, 0, stream>>>(ecol, hist, E, chunk);
  {
    const int nh = NB * NBLK;
    const int nbh = (nh + SCAN_VPB - 1) / SCAN_VPB;
    scanA<<<nbh, SCAN_T, 0, stream>>>(hist, histBase, blockTotals, nh);
    scanB<<<1, 64, 0, stream>>>(blockTotals, nbh);
    scanC<<<(nh + 255) / 256, 256, 0, stream>>>(histBase, blockTotals, nh);
  }
  edge_partition<<<NBLK, 256, 0, stream>>>(erow, ecol, histBase, part, E, chunk);
  bucket_cnt<<<NB, 256, 0, stream>>>(part, histBase, deg, dis, padTot, N);
  padscan<<<1, 64, 0, stream>>>(padTot, padBase, NB);
  bucket_ew<<<NB, 256, 0, stream>>>(part, histBase, padBase, deg, dis,
                                    offsets, dend, ew, N);

  // fused casts (x + both weights)
  {
    int tot = N * 64 + INC * HIDC + HIDC * HIDC;
    cast_all<<<(tot + 255) / 256, 256, 0, stream>>>(x, x_cb, W1, W1T, W2, W2T, N);
  }

  // layer 1: XCD-pinned cb aggregate (4 slices), GEMM -> h1 cb
  {
    const int nb2 = (N + 63) / 64;
    aggregate_cb<1><<<nb2 << 3, 256, 0, stream>>>(
        (const uint2*)x_cb, dis, offsets, dend, ew, (uint2*)agg1_cb, N);
  }
  {
    dim3 grid((N + 127) / 128, HIDC / 128);
    gemm_mfma<INC, true><<<grid, 256, 0, stream>>>(
        (const ushort*)agg1_cb, W1T, b1, (ushort*)h1_cb, N);
  }
  // layer 2: XCD-pinned cb aggregate (8 slices), GEMM -> h2 row-major
  {
    const int nodeblks = (N + 31) / 32;
    aggregate_cb<0><<<nodeblks << 3, 256, 0, stream>>>(
        (const uint2*)h1_cb, dis, offsets, dend, ew, (uint2*)agg2_cb, N);
  }
  {
    dim3 grid((N + 127) / 128, HIDC / 128);
    gemm_mfma<HIDC, false><<<grid, 256, 0, stream>>>(
        (const ushort*)agg2_cb, W2T, b2, h2, N);
  }
  // pool (partials, no atomics) + MLP
  {
    dim3 pgrid(NG, POOL_SPLIT);
    pool_partial<<<pgrid, HIDC, 0, stream>>>(h2, batch, psum, N);
  }
  mlp_kernel<<<NG, 64, 0, stream>>>(psum, batch, Wl1, bl1, Wl2, bl2, out, N);
}